// Round 2
// baseline (123.954 us; speedup 1.0000x reference)
//
#include <hip/hip_runtime.h>
#include <hip/hip_bf16.h>

#define NN 8192
#define INF_ 256
#define OUTF 64
#define ALPHA 0.2f
#define LOG2E 1.44269504088896f

typedef __attribute__((ext_vector_type(8))) short short8;
typedef __attribute__((ext_vector_type(4))) float f32x4;

static __device__ __forceinline__ unsigned short f2bf(float f) {
  unsigned u = __builtin_bit_cast(unsigned, f);
  u += 0x7fffu + ((u >> 16) & 1u);          // RNE; inputs are finite
  return (unsigned short)(u >> 16);
}

static __device__ __forceinline__ float pval(int a, float s2v, float s1v, float msc) {
  const float x = s1v + s2v;
  const float lr = fmaxf(x, ALPHA * x);      // leaky_relu, alpha<1
  const float e = exp2f(fmaf(lr, LOG2E, -msc));
  return a > 0 ? e : 0.f;
}

static __device__ __forceinline__ ushort4 p4(const int4 a, const float4 s,
                                             float s1v, float msc, float& lp) {
  const float p0 = pval(a.x, s.x, s1v, msc);
  const float p1 = pval(a.y, s.y, s1v, msc);
  const float p2 = pval(a.z, s.z, s1v, msc);
  const float p3 = pval(a.w, s.w, s1v, msc);
  lp += (p0 + p1) + (p2 + p3);
  ushort4 r;
  r.x = f2bf(p0); r.y = f2bf(p1); r.z = f2bf(p2); r.w = f2bf(p3);
  return r;
}

// ---------------- Kernel A: h' = X@W  ->  hp_t (bf16, transposed), s1, s2, per-block s2max
__global__ __launch_bounds__(256) void k_prep(
    const float* __restrict__ X, const float* __restrict__ W,
    const float* __restrict__ a1, const float* __restrict__ a2,
    unsigned short* __restrict__ hpt, float* __restrict__ s1,
    float* __restrict__ s2, float* __restrict__ pmax)
{
  __shared__ float Ws[INF_ * OUTF];   // 64 KB
  __shared__ float Xs[32 * INF_];     // 32 KB
  __shared__ float sm8[8];
  const int t = threadIdx.x;
  const int ib = blockIdx.x;

  #pragma unroll
  for (int i = 0; i < 16; ++i) {
    const int idx = (i * 256 + t) * 4;
    *reinterpret_cast<float4*>(&Ws[idx]) = *reinterpret_cast<const float4*>(&W[idx]);
  }
  const float* Xb = X + (size_t)ib * 32 * INF_;
  #pragma unroll
  for (int i = 0; i < 8; ++i) {
    const int idx = (i * 256 + t) * 4;
    *reinterpret_cast<float4*>(&Xs[idx]) = *reinterpret_cast<const float4*>(&Xb[idx]);
  }
  __syncthreads();

  const int rg = t >> 5;          // 0..7 -> rows 4*rg..4*rg+3
  const int r0 = rg * 4;
  const int c0 = 2 * (t & 31);    // 2 consecutive output features
  float acc[4][2] = {{0.f,0.f},{0.f,0.f},{0.f,0.f},{0.f,0.f}};

  for (int k = 0; k < INF_; k += 4) {
    float xv[4][4];
    #pragma unroll
    for (int rr = 0; rr < 4; ++rr)
      *reinterpret_cast<float4*>(&xv[rr][0]) =
          *reinterpret_cast<const float4*>(&Xs[(r0 + rr) * INF_ + k]);
    #pragma unroll
    for (int kk = 0; kk < 4; ++kk) {
      const float2 wv = *reinterpret_cast<const float2*>(&Ws[(k + kk) * OUTF + c0]);
      #pragma unroll
      for (int rr = 0; rr < 4; ++rr) {
        acc[rr][0] = fmaf(xv[rr][kk], wv.x, acc[rr][0]);
        acc[rr][1] = fmaf(xv[rr][kk], wv.y, acc[rr][1]);
      }
    }
  }

  // s1/s2 partials from f32 accumulators
  const float a10 = a1[c0], a11 = a1[c0 + 1];
  const float a20 = a2[c0], a21 = a2[c0 + 1];
  float sp1[4], sp2[4];
  #pragma unroll
  for (int rr = 0; rr < 4; ++rr) {
    sp1[rr] = acc[rr][0] * a10 + acc[rr][1] * a11;
    sp2[rr] = acc[rr][0] * a20 + acc[rr][1] * a21;
  }
  #pragma unroll
  for (int d = 1; d < 32; d <<= 1) {
    #pragma unroll
    for (int rr = 0; rr < 4; ++rr) {
      sp1[rr] += __shfl_xor(sp1[rr], d, 64);
      sp2[rr] += __shfl_xor(sp2[rr], d, 64);
    }
  }

  // hp_t[f][node] bf16 — thread owns 4 consecutive rows -> 8B stores
  const int gr = ib * 32 + r0;
  #pragma unroll
  for (int cc = 0; cc < 2; ++cc) {
    ushort4 pk;
    pk.x = f2bf(acc[0][cc]); pk.y = f2bf(acc[1][cc]);
    pk.z = f2bf(acc[2][cc]); pk.w = f2bf(acc[3][cc]);
    *reinterpret_cast<ushort4*>(&hpt[(size_t)(c0 + cc) * NN + gr]) = pk;
  }
  if ((t & 31) == 0) {
    #pragma unroll
    for (int rr = 0; rr < 4; ++rr) { s1[gr + rr] = sp1[rr]; s2[gr + rr] = sp2[rr]; }
    sm8[rg] = fmaxf(fmaxf(sp2[0], sp2[1]), fmaxf(sp2[2], sp2[3]));
  }
  __syncthreads();
  if (t == 0) {
    float m = sm8[0];
    #pragma unroll
    for (int i = 1; i < 8; ++i) m = fmaxf(m, sm8[i]);
    pmax[ib] = m;
  }
}

// ---------------- Kernel R: global max of s2
__global__ void k_rmax(const float* __restrict__ pmax, float* __restrict__ s2max) {
  const int t = threadIdx.x;  // 64 threads
  float m = fmaxf(fmaxf(pmax[t], pmax[t + 64]), fmaxf(pmax[t + 128], pmax[t + 192]));
  #pragma unroll
  for (int d = 1; d < 64; d <<= 1) m = fmaxf(m, __shfl_xor(m, d, 64));
  if (t == 0) *s2max = m;
}

// ---------------- Kernel C: fused masked-softmax + attn@h' + elu — barrier-free streaming
// 512 blocks x 512 thr. Block owns 16 output rows. 8 waves split K 8-ways (1024 each).
// Each wave computes its MFMA A-fragment p-values directly in registers (no LDS, no
// per-tile barrier); one final LDS reduction combines the 8 K-chunk partials.
__global__ __launch_bounds__(512, 4) void k_main(
    const int* __restrict__ adj, const unsigned short* __restrict__ hpt,
    const float* __restrict__ s1g, const float* __restrict__ s2g,
    const float* __restrict__ s2max, float* __restrict__ out)
{
  __shared__ float red[8][64][17];   // +1 pad: lane stride 17 floats -> conflict-free
  __shared__ float lden[8][16];
  const int t = threadIdx.x;
  const int lane = t & 63;
  const int w = t >> 6;            // K-chunk id 0..7
  const int rb = blockIdx.x;       // row-tile
  const int r15 = lane & 15;       // A-fragment row within tile
  const int kq = lane >> 4;        // k-quad 0..3 (8 cols each)
  const int row = rb * 16 + r15;

  const float s1v = s1g[row];
  const float SM = *s2max;
  const float xm = s1v + SM;
  const float msc = fmaxf(xm, ALPHA * xm) * LOG2E;  // M_i*log2e, M_i >= row max (lrelu monotone)

  const int kbase = w * 1024 + kq * 8;
  const int* aP = adj + (size_t)row * NN + kbase;
  const float* sP = s2g + kbase;
  const unsigned short* bP = hpt + (size_t)r15 * NN + w * 1024 + kq * 8;

  f32x4 acc0 = {0.f,0.f,0.f,0.f}, acc1 = acc0, acc2 = acc0, acc3 = acc0;
  float lpart = 0.f;

  // prefetch k-step 0
  int4  a0 = *reinterpret_cast<const int4*>(aP);
  int4  a1 = *reinterpret_cast<const int4*>(aP + 4);
  float4 sA = *reinterpret_cast<const float4*>(sP);
  float4 sB = *reinterpret_cast<const float4*>(sP + 4);
  short8 b0 = *reinterpret_cast<const short8*>(bP);
  short8 b1 = *reinterpret_cast<const short8*>(bP + 16 * NN);
  short8 b2 = *reinterpret_cast<const short8*>(bP + 32 * NN);
  short8 b3 = *reinterpret_cast<const short8*>(bP + 48 * NN);

  for (int st = 0; st < 32; ++st) {
    const int nk = (st < 31) ? (st + 1) * 32 : 0;   // tail reloads step0 (discarded)
    const int4  na0 = *reinterpret_cast<const int4*>(aP + nk);
    const int4  na1 = *reinterpret_cast<const int4*>(aP + nk + 4);
    const float4 nsA = *reinterpret_cast<const float4*>(sP + nk);
    const float4 nsB = *reinterpret_cast<const float4*>(sP + nk + 4);
    const short8 nb0 = *reinterpret_cast<const short8*>(bP + nk);
    const short8 nb1 = *reinterpret_cast<const short8*>(bP + nk + 16 * NN);
    const short8 nb2 = *reinterpret_cast<const short8*>(bP + nk + 32 * NN);
    const short8 nb3 = *reinterpret_cast<const short8*>(bP + nk + 48 * NN);

    const ushort4 lo = p4(a0, sA, s1v, msc, lpart);
    const ushort4 hi = p4(a1, sB, s1v, msc, lpart);
    short8 af;
    af[0] = (short)lo.x; af[1] = (short)lo.y; af[2] = (short)lo.z; af[3] = (short)lo.w;
    af[4] = (short)hi.x; af[5] = (short)hi.y; af[6] = (short)hi.z; af[7] = (short)hi.w;
    acc0 = __builtin_amdgcn_mfma_f32_16x16x32_bf16(af, b0, acc0, 0, 0, 0);
    acc1 = __builtin_amdgcn_mfma_f32_16x16x32_bf16(af, b1, acc1, 0, 0, 0);
    acc2 = __builtin_amdgcn_mfma_f32_16x16x32_bf16(af, b2, acc2, 0, 0, 0);
    acc3 = __builtin_amdgcn_mfma_f32_16x16x32_bf16(af, b3, acc3, 0, 0, 0);

    a0 = na0; a1 = na1; sA = nsA; sB = nsB;
    b0 = nb0; b1 = nb1; b2 = nb2; b3 = nb3;
  }

  // per-row denominator partial for this K-chunk: combine the 4 k-quads
  lpart += __shfl_xor(lpart, 16, 64);
  lpart += __shfl_xor(lpart, 32, 64);
  if (kq == 0) lden[w][r15] = lpart;

  // dump accumulators for cross-wave (K-chunk) reduction
  #pragma unroll
  for (int r = 0; r < 4; ++r) {
    red[w][lane][r]      = acc0[r];
    red[w][lane][4 + r]  = acc1[r];
    red[w][lane][8 + r]  = acc2[r];
    red[w][lane][12 + r] = acc3[r];
  }
  __syncthreads();

  // 1024 outputs / 512 threads = 2 each. C/D layout: col = s*16 + (lane&15),
  // row = (lane>>4)*4 + reg  ->  lane = (row>>2)*16 + c, idx = s*4 + (row&3)
  const int orow = t >> 5;     // 0..15
  const int oc = t & 31;       // cols oc and oc+32
  float den = 0.f;
  #pragma unroll
  for (int ww = 0; ww < 8; ++ww) den += lden[ww][orow];
  const float inv = 1.f / den;
  #pragma unroll
  for (int half = 0; half < 2; ++half) {
    const int col = oc + 32 * half;
    const int s = col >> 4, c = col & 15;
    const int li = (orow >> 2) * 16 + c;
    const int ri = s * 4 + (orow & 3);
    float v = 0.f;
    #pragma unroll
    for (int ww = 0; ww < 8; ++ww) v += red[ww][li][ri];
    const float dv = v * inv;
    out[(size_t)(rb * 16 + orow) * OUTF + col] = dv > 0.f ? dv : (expf(dv) - 1.f);
  }
}

extern "C" void kernel_launch(void* const* d_in, const int* in_sizes, int n_in,
                              void* d_out, int out_size, void* d_ws, size_t ws_size,
                              hipStream_t stream) {
  (void)in_sizes; (void)n_in; (void)out_size; (void)ws_size;
  const float* X  = (const float*)d_in[0];
  const int* adj  = (const int*)d_in[1];
  const float* W  = (const float*)d_in[2];
  const float* a1 = (const float*)d_in[3];
  const float* a2 = (const float*)d_in[4];
  float* out = (float*)d_out;

  char* ws = (char*)d_ws;
  unsigned short* hpt = (unsigned short*)ws;                    // 64*8192*2 = 1 MB
  float* s1   = (float*)(ws + (size_t)OUTF * NN * 2);           // 32 KB
  float* s2   = s1 + NN;                                        // 32 KB
  float* pmax = s2 + NN;                                        // 1 KB
  float* s2m  = pmax + 256;                                     // 4 B

  hipLaunchKernelGGL(k_prep, dim3(256), dim3(256), 0, stream, X, W, a1, a2, hpt, s1, s2, pmax);
  hipLaunchKernelGGL(k_rmax, dim3(1), dim3(64), 0, stream, pmax, s2m);
  hipLaunchKernelGGL(k_main, dim3(512), dim3(512), 0, stream, adj, hpt, s1, s2, s2m, out);
}